// Round 11
// baseline (357.765 us; speedup 1.0000x reference)
//
#include <hip/hip_runtime.h>

namespace {
constexpr int Sdim = 128;
constexpr int Tdim = 64;
constexpr int U2c  = 16;
constexpr int PT   = 64;                 // pixel span per block -> 256B yt segments
constexpr int NTHREADS = 512;
constexpr int PP = Sdim * Sdim;          // 16384 pixels
constexpr int TQ = 8;                    // t-steps per stage (32 KiB per buffer)
constexpr int NSTG = Tdim / TQ;          // 8 stages
}

// A/B vs R10: identical waves/CU (8), acc (128), LDS bytes/FMA; ONLY the yt/global
// segment size changes (128B -> 256B contiguous, 1KB/instr via float4 over 4p).
// (512,2): VGPR cap 256, need ~190 -> no clamp-spill (R2/R9 lesson).
__global__ __launch_bounds__(NTHREADS, 2)
void upscale_fused(const float* __restrict__ yt,
                   const float* __restrict__ wgt,
                   const float* __restrict__ bias,
                   float* __restrict__ out)
{
    // Double-buffered weight tile, layout [t_local][u][col], col = p ^ (4*t_local).
    // Reads: ds_read_b128 at 16 distinct 16B slots spanning 256B -> 2-way (free)
    // + 4-way b-broadcast (free). Writes: 16 cols -> 4-way, amortized.
    __shared__ float wlds[2][TQ * U2c * PT];   // 2 x 32 KiB

    const int tid   = threadIdx.x;
    const int p_blk = blockIdx.x * PT;

    const int pg = tid & 15;            // 4 p's: p0 = p_blk + pg*4
    const int b2 = tid >> 4;            // 0..31: b in {b2, b2+32}
    const int p0 = p_blk + pg * 4;

    const float4* wgt4 = reinterpret_cast<const float4*>(wgt);

    // ---- stage weights for t in [stg*8, stg*8+8) into buf ------------------------
    // global: per p-row a contiguous 512B chunk; wave reads 2 rows x 512B runs.
    auto stage = [&](int stg, int buf) {
        #pragma unroll
        for (int i = 0; i < 4; ++i) {
            const int f = i * NTHREADS + tid;    // 0..2047 float4s of the 32KB tile
            const int r = f >> 5;                // p row 0..63
            const int c = f & 31;                // float4 within the 512B p-chunk
            const float4 v = wgt4[(size_t)(p_blk + r) * 256 + (size_t)stg * 32 + c];
            const int tl = c >> 2;               // t_local 0..7
            const int uq = c & 3;                // u quad
            const int col = r ^ (4 * tl);        // quad-preserving XOR swizzle
            float* dst = &wlds[buf][(tl * U2c + uq * 4) * PT + col];
            dst[0 * PT] = v.x;  dst[1 * PT] = v.y;
            dst[2 * PT] = v.z;  dst[3 * PT] = v.w;
        }
    };

    stage(0, 0);

    // ---- init acc with bias (identical for both b) -------------------------------
    float acc[2][4][16];   // [bi][j(p)][u]
    #pragma unroll
    for (int j = 0; j < 4; ++j) {
        const float* bp = bias + (size_t)(p0 + j) * U2c;
        #pragma unroll
        for (int q = 0; q < 4; ++q) {
            const float4 v = *reinterpret_cast<const float4*>(bp + q * 4);
            acc[0][j][q * 4 + 0] = v.x;  acc[0][j][q * 4 + 1] = v.y;
            acc[0][j][q * 4 + 2] = v.z;  acc[0][j][q * 4 + 3] = v.w;
            acc[1][j][q * 4 + 0] = v.x;  acc[1][j][q * 4 + 1] = v.y;
            acc[1][j][q * 4 + 2] = v.z;  acc[1][j][q * 4 + 3] = v.w;
        }
    }

    // ---- yt: float4 per (b,t): 16 lanes x 16B = 256B segment, 4 segs = 1KB/instr -
    const float* y0b = yt + (size_t)b2 * ((size_t)Tdim * PP) + p0;
    const float* y1b = y0b + (size_t)32 * Tdim * PP;
    float4 yc[2], yn[2];
    auto ldy = [&](int t, float4* dst) {
        dst[0] = *reinterpret_cast<const float4*>(y0b + (size_t)t * PP);
        dst[1] = *reinterpret_cast<const float4*>(y1b + (size_t)t * PP);
    };

    auto step = [&](const float4* y, int tl, int buf) {
        const float* base = &wlds[buf][tl * (U2c * PT) + ((pg * 4) ^ (4 * tl))];
        #pragma unroll
        for (int u = 0; u < 16; ++u) {
            const float4 wv = *reinterpret_cast<const float4*>(base + u * PT);
            acc[0][0][u] = fmaf(y[0].x, wv.x, acc[0][0][u]);
            acc[0][1][u] = fmaf(y[0].y, wv.y, acc[0][1][u]);
            acc[0][2][u] = fmaf(y[0].z, wv.z, acc[0][2][u]);
            acc[0][3][u] = fmaf(y[0].w, wv.w, acc[0][3][u]);
            acc[1][0][u] = fmaf(y[1].x, wv.x, acc[1][0][u]);
            acc[1][1][u] = fmaf(y[1].y, wv.y, acc[1][1][u]);
            acc[1][2][u] = fmaf(y[1].z, wv.z, acc[1][2][u]);
            acc[1][3][u] = fmaf(y[1].w, wv.w, acc[1][3][u]);
        }
    };

    // ---- depth-2 ping-pong yt ring (static indexing) -----------------------------
    ldy(0, yc);
    ldy(1, yn);

    __syncthreads();   // stage 0 visible

    #pragma unroll 1
    for (int stg = 0; stg < NSTG; ++stg) {
        const int buf = stg & 1;
        if (stg + 1 < NSTG) stage(stg + 1, buf ^ 1);   // writes other buffer: no race

        #pragma unroll 1
        for (int tq = 0; tq < TQ; tq += 2) {
            const int tg = stg * TQ + tq;
            step(yc, tq, buf);
            if (tg + 2 < Tdim) ldy(tg + 2, yc);
            step(yn, tq + 1, buf);
            if (tg + 3 < Tdim) ldy(tg + 3, yn);
        }
        if (stg + 1 < NSTG) __syncthreads();   // one barrier per stage
    }

    // ---- epilogue: pixel-shuffle scatter; wave = 4 x 256B segments ---------------
    const int s1   = p_blk / Sdim;
    const int s2_0 = p_blk % Sdim;

    #pragma unroll
    for (int bi = 0; bi < 2; ++bi) {
        const int b = b2 + bi * 32;
        float* ob = out + (size_t)b * (512 * 512);
        #pragma unroll
        for (int j = 0; j < 4; ++j) {
            const int c0 = (s2_0 + pg * 4 + j) * 4;
            #pragma unroll
            for (int u1 = 0; u1 < 4; ++u1) {
                const int r = s1 * 4 + u1;
                float4 v;
                v.x = acc[bi][j][u1 * 4 + 0];
                v.y = acc[bi][j][u1 * 4 + 1];
                v.z = acc[bi][j][u1 * 4 + 2];
                v.w = acc[bi][j][u1 * 4 + 3];
                *reinterpret_cast<float4*>(ob + (size_t)r * 512 + c0) = v;
            }
        }
    }
}

extern "C" void kernel_launch(void* const* d_in, const int* in_sizes, int n_in,
                              void* d_out, int out_size, void* d_ws, size_t ws_size,
                              hipStream_t stream)
{
    const float* yt   = (const float*)d_in[0];
    const float* wgt  = (const float*)d_in[1];
    const float* bias = (const float*)d_in[2];
    float* outp       = (float*)d_out;

    dim3 grid(PP / PT);     // 256 blocks x 512 threads -> 1 block/CU
    dim3 block(NTHREADS);
    hipLaunchKernelGGL(upscale_fused, grid, block, 0, stream, yt, wgt, bias, outp);
}

// Round 12
// 357.019 us; speedup vs baseline: 1.0021x; 1.0021x over previous
//
#include <hip/hip_runtime.h>

namespace {
constexpr int Sdim = 128;
constexpr int Tdim = 64;
constexpr int U2c  = 16;
constexpr int PT   = 64;                 // pixel span per block -> 256B yt segments
constexpr int NTHREADS = 512;
constexpr int PP = Sdim * Sdim;          // 16384 pixels
constexpr int TQ = 8;                    // t-steps per stage (32 KiB per buffer)
constexpr int NSTG = Tdim / TQ;          // 8 stages
}

// A/B vs R10: identical waves/CU (8), acc (128), LDS bytes/FMA; ONLY the yt/global
// segment size changes (128B -> 256B contiguous, 1KB/instr via float4 over 4p).
// NO second launch_bounds arg: (512,2) empirically caps VGPR at 128 (R11: 825MB
// spill). One 8-wave block = 2 waves/SIMD -> natural cap 256 >= ~190 need.
__global__ __launch_bounds__(NTHREADS)
void upscale_fused(const float* __restrict__ yt,
                   const float* __restrict__ wgt,
                   const float* __restrict__ bias,
                   float* __restrict__ out)
{
    // Double-buffered weight tile, layout [t_local][u][col], col = p ^ (4*t_local).
    // Reads: ds_read_b128 at 16 distinct 16B slots spanning 256B -> 2-way (free)
    // + 4-way b-broadcast (free). Writes: 16 cols -> 4-way, amortized.
    __shared__ float wlds[2][TQ * U2c * PT];   // 2 x 32 KiB

    const int tid   = threadIdx.x;
    const int p_blk = blockIdx.x * PT;

    const int pg = tid & 15;            // 4 p's: p0 = p_blk + pg*4
    const int b2 = tid >> 4;            // 0..31: b in {b2, b2+32}
    const int p0 = p_blk + pg * 4;

    const float4* wgt4 = reinterpret_cast<const float4*>(wgt);

    // ---- stage weights for t in [stg*8, stg*8+8) into buf ------------------------
    // global: per p-row a contiguous 512B chunk; wave reads 1KB contiguous runs.
    auto stage = [&](int stg, int buf) {
        #pragma unroll
        for (int i = 0; i < 4; ++i) {
            const int f = i * NTHREADS + tid;    // 0..2047 float4s of the 32KB tile
            const int r = f >> 5;                // p row 0..63
            const int c = f & 31;                // float4 within the 512B p-chunk
            const float4 v = wgt4[(size_t)(p_blk + r) * 256 + (size_t)stg * 32 + c];
            const int tl = c >> 2;               // t_local 0..7
            const int uq = c & 3;                // u quad
            const int col = r ^ (4 * tl);        // quad-preserving XOR swizzle
            float* dst = &wlds[buf][(tl * U2c + uq * 4) * PT + col];
            dst[0 * PT] = v.x;  dst[1 * PT] = v.y;
            dst[2 * PT] = v.z;  dst[3 * PT] = v.w;
        }
    };

    stage(0, 0);

    // ---- init acc with bias (identical for both b) -------------------------------
    float acc[2][4][16];   // [bi][j(p)][u]
    #pragma unroll
    for (int j = 0; j < 4; ++j) {
        const float* bp = bias + (size_t)(p0 + j) * U2c;
        #pragma unroll
        for (int q = 0; q < 4; ++q) {
            const float4 v = *reinterpret_cast<const float4*>(bp + q * 4);
            acc[0][j][q * 4 + 0] = v.x;  acc[0][j][q * 4 + 1] = v.y;
            acc[0][j][q * 4 + 2] = v.z;  acc[0][j][q * 4 + 3] = v.w;
            acc[1][j][q * 4 + 0] = v.x;  acc[1][j][q * 4 + 1] = v.y;
            acc[1][j][q * 4 + 2] = v.z;  acc[1][j][q * 4 + 3] = v.w;
        }
    }

    // ---- yt: float4 per (b,t): 16 lanes x 16B = 256B segment, 4 segs = 1KB/instr -
    const float* y0b = yt + (size_t)b2 * ((size_t)Tdim * PP) + p0;
    const float* y1b = y0b + (size_t)32 * Tdim * PP;
    float4 yc[2], yn[2];
    auto ldy = [&](int t, float4* dst) {
        dst[0] = *reinterpret_cast<const float4*>(y0b + (size_t)t * PP);
        dst[1] = *reinterpret_cast<const float4*>(y1b + (size_t)t * PP);
    };

    auto step = [&](const float4* y, int tl, int buf) {
        const float* base = &wlds[buf][tl * (U2c * PT) + ((pg * 4) ^ (4 * tl))];
        #pragma unroll
        for (int u = 0; u < 16; ++u) {
            const float4 wv = *reinterpret_cast<const float4*>(base + u * PT);
            acc[0][0][u] = fmaf(y[0].x, wv.x, acc[0][0][u]);
            acc[0][1][u] = fmaf(y[0].y, wv.y, acc[0][1][u]);
            acc[0][2][u] = fmaf(y[0].z, wv.z, acc[0][2][u]);
            acc[0][3][u] = fmaf(y[0].w, wv.w, acc[0][3][u]);
            acc[1][0][u] = fmaf(y[1].x, wv.x, acc[1][0][u]);
            acc[1][1][u] = fmaf(y[1].y, wv.y, acc[1][1][u]);
            acc[1][2][u] = fmaf(y[1].z, wv.z, acc[1][2][u]);
            acc[1][3][u] = fmaf(y[1].w, wv.w, acc[1][3][u]);
        }
    };

    // ---- depth-2 ping-pong yt ring (static indexing) -----------------------------
    ldy(0, yc);
    ldy(1, yn);

    __syncthreads();   // stage 0 visible

    #pragma unroll 1
    for (int stg = 0; stg < NSTG; ++stg) {
        const int buf = stg & 1;
        if (stg + 1 < NSTG) stage(stg + 1, buf ^ 1);   // writes other buffer: no race

        #pragma unroll 1
        for (int tq = 0; tq < TQ; tq += 2) {
            const int tg = stg * TQ + tq;
            step(yc, tq, buf);
            if (tg + 2 < Tdim) ldy(tg + 2, yc);
            step(yn, tq + 1, buf);
            if (tg + 3 < Tdim) ldy(tg + 3, yn);
        }
        if (stg + 1 < NSTG) __syncthreads();   // one barrier per stage
    }

    // ---- epilogue: pixel-shuffle scatter; wave = 4 x 256B segments ---------------
    const int s1   = p_blk / Sdim;
    const int s2_0 = p_blk % Sdim;

    #pragma unroll
    for (int bi = 0; bi < 2; ++bi) {
        const int b = b2 + bi * 32;
        float* ob = out + (size_t)b * (512 * 512);
        #pragma unroll
        for (int j = 0; j < 4; ++j) {
            const int c0 = (s2_0 + pg * 4 + j) * 4;
            #pragma unroll
            for (int u1 = 0; u1 < 4; ++u1) {
                const int r = s1 * 4 + u1;
                float4 v;
                v.x = acc[bi][j][u1 * 4 + 0];
                v.y = acc[bi][j][u1 * 4 + 1];
                v.z = acc[bi][j][u1 * 4 + 2];
                v.w = acc[bi][j][u1 * 4 + 3];
                *reinterpret_cast<float4*>(ob + (size_t)r * 512 + c0) = v;
            }
        }
    }
}

extern "C" void kernel_launch(void* const* d_in, const int* in_sizes, int n_in,
                              void* d_out, int out_size, void* d_ws, size_t ws_size,
                              hipStream_t stream)
{
    const float* yt   = (const float*)d_in[0];
    const float* wgt  = (const float*)d_in[1];
    const float* bias = (const float*)d_in[2];
    float* outp       = (float*)d_out;

    dim3 grid(PP / PT);     // 256 blocks x 512 threads -> 1 block/CU
    dim3 block(NTHREADS);
    hipLaunchKernelGGL(upscale_fused, grid, block, 0, stream, yt, wgt, bias, outp);
}